// Round 7
// baseline (129.935 us; speedup 1.0000x reference)
//
#include <hip/hip_runtime.h>
#include <hip/hip_bf16.h>
#include <cstdint>

#define N_SPK 1024
#define M_UTT 20
#define D_DIM 768
#define NM_ROWS (N_SPK * M_UTT)   // 20480 utterances / rows

static constexpr float EPS = 1e-8f;

// s_waitcnt immediates (gfx9): vmcnt[3:0]=bits3:0, expcnt=6:4, lgkmcnt=11:8,
// vmcnt[5:4]=bits15:14.
#define WAIT_VM0   0x0F70   // vmcnt=0,  lgkm/exp no-wait
#define WAIT_VM8   0x0F78   // vmcnt=8,  lgkm/exp no-wait
#define WAIT_LGKM0 0xC07F   // lgkmcnt=0, vmcnt/exp no-wait

typedef __attribute__((ext_vector_type(4))) float floatx4;  // MFMA accumulator
typedef __attribute__((ext_vector_type(4))) int   intx4;    // 16B LDS read
typedef __attribute__((ext_vector_type(8))) int   intx8;    // 32B MFMA operand

__device__ __forceinline__ void load16_to_lds(const void* g, void* l) {
    __builtin_amdgcn_global_load_lds(
        (const __attribute__((address_space(1))) uint32_t*)g,
        (__attribute__((address_space(3))) uint32_t*)l, 16, 0, 0);
}

__device__ __forceinline__ float wave_sum(float v) {
    #pragma unroll
    for (int o = 32; o > 0; o >>= 1) v += __shfl_xor(v, o);
    return v;
}

// pack two f32 -> two OCP e4m3 bytes (low word of result)
__device__ __forceinline__ unsigned short fp8pk(float a, float b) {
    return (unsigned short)(__builtin_amdgcn_cvt_pk_fp8_f32(a, b, 0, false) & 0xFFFF);
}

// K-interleave permutation (prep-time, within each 64-byte K-block). Applied
// identically to ehat and chat; the gemm reads both operands through identical
// addressing, so this global k-bijection cancels in the MFMA dot product
// (validated empirically: absmax 0.0 in R5/R6).
__device__ __forceinline__ int kperm(int d) {
    return (d & ~63) | (((d >> 3) & 3) << 4) | (((d >> 5) & 1) << 3) | (d & 7);
}

// ---------------------------------------------------------------------------
// Kernel 1 (prep): per speaker, read emb once (float2/thread, 384 thr),
// centroid + 20 utterance norms; write FP8 e4m3 Ehat ([m][i][dp]) and Chat.
// Zero-inits ctr/accum.  (unchanged — isolate the gemm change)
// ---------------------------------------------------------------------------
__global__ __launch_bounds__(384) void prep_kernel(const float* __restrict__ emb,
                                                   unsigned char* __restrict__ ehat,
                                                   unsigned char* __restrict__ chat,
                                                   int* __restrict__ ctr,
                                                   float* __restrict__ accum) {
    const int i = blockIdx.x;      // speaker
    const int t = threadIdx.x;     // 0..383
    const int wave = t >> 6, lane = t & 63;

    if (i == 0 && t == 0) { *ctr = 0; *accum = 0.f; }

    const float2* src = (const float2*)(emb + (size_t)i * M_UTT * D_DIM);
    const int dp = kperm(t * 2);   // byte index of the fp8 pair in stored layout

    float2 v[M_UTT];
    float ss[M_UTT];
    float2 cen = {0.f, 0.f};
    #pragma unroll
    for (int m = 0; m < M_UTT; ++m) {
        const float2 x = src[m * 384 + t];
        v[m] = x;
        ss[m] = x.x * x.x + x.y * x.y;
        cen.x += x.x; cen.y += x.y;
    }
    cen.x *= (1.f / M_UTT); cen.y *= (1.f / M_UTT);
    float css = cen.x * cen.x + cen.y * cen.y;

    __shared__ float red[M_UTT + 1][6];
    #pragma unroll
    for (int m = 0; m < M_UTT; ++m) {
        const float s = wave_sum(ss[m]);
        if (lane == 0) red[m][wave] = s;
    }
    {
        const float s = wave_sum(css);
        if (lane == 0) red[M_UTT][wave] = s;
    }
    __syncthreads();

    #pragma unroll
    for (int m = 0; m < M_UTT; ++m) {
        const float tot = red[m][0] + red[m][1] + red[m][2] +
                          red[m][3] + red[m][4] + red[m][5];
        const float rn = 1.0f / fmaxf(sqrtf(tot), EPS);
        *(unsigned short*)(ehat + ((size_t)(m * N_SPK + i)) * D_DIM + dp) =
            fp8pk(v[m].x * rn, v[m].y * rn);
    }
    {
        const float tot = red[M_UTT][0] + red[M_UTT][1] + red[M_UTT][2] +
                          red[M_UTT][3] + red[M_UTT][4] + red[M_UTT][5];
        const float rn = 1.0f / fmaxf(sqrtf(tot), EPS);
        *(unsigned short*)(chat + (size_t)i * D_DIM + dp) =
            fp8pk(cen.x * rn, cen.y * rn);
    }
}

// ---------------------------------------------------------------------------
// Kernel 2: 128x128 tile, 4 waves (2x2 quadrants of 64x64), BK=128, 6 K-iters,
// MX-scaled fp8 MFMA (unit scales) — R6 datapath kept byte-for-byte.
//   R7 change: T3/T4 counted-vmcnt schedule. Per iter:
//     top:  s_waitcnt vmcnt(8)  [tile kt = oldest 8; kt+1's 8 stay in flight]
//           s_barrier           [collectively: tile kt fully in LDS]
//     compute(kt) from buf[kt&1]
//     if kt<4: s_waitcnt lgkmcnt(0); s_barrier  [all waves' ds_reads retired]
//              stage tile kt+2 -> buf[kt&1]     [issue-after-reads => WAR-safe]
//   No vmcnt(0) drain in the main loop (only kt=5). Steady-state wait targets
//   loads issued a full iteration earlier -> exposed L2 latency ~0.
//   s_setprio(1) around the MFMA cluster (2 staggered blocks/CU arbitrate).
// ---------------------------------------------------------------------------
__global__ __launch_bounds__(256, 2) void gemm_fused_kernel(
        const unsigned char* __restrict__ ehat,
        const unsigned char* __restrict__ chat,
        const float* __restrict__ wp,
        float* __restrict__ Psum,
        float* __restrict__ T) {
    __shared__ unsigned char As[2][128 * 128];   // 2 x 16 KB
    __shared__ unsigned char Bs[2][128 * 128];   // 2 x 16 KB

    const int t    = threadIdx.x;
    const int lane = t & 63;
    const int wid  = t >> 6;        // 0..3
    const int c    = lane & 15;
    const int quad = lane >> 4;
    const int wr   = wid >> 1;      // row quadrant 0..1
    const int wc   = wid & 1;       // col quadrant 0..1

    const int xcd = blockIdx.x & 7;
    const int idx = blockIdx.x >> 3;        // 0..159 per XCD
    const int bu  = xcd * 20 + (idx >> 3);  // 0..159 (128-row tiles)
    const int bj  = idx & 7;                // 0..7   (bj fastest within XCD)
    const int m   = bu >> 3;                // 8 bu-tiles per m
    const int rb8 = bu & 7;
    const int u0  = bu * 128;
    const int j0  = bj * 128;

    const unsigned char* Ag = ehat + (size_t)u0 * D_DIM;
    const unsigned char* Bg = chat + (size_t)j0 * D_DIM;

    // staging: 1024 16B chunks per operand tile; ci = s*256 + t, s=0..3.
    // Dest LINEAR at ci*16; global source chunk pre-swizzled:
    // phys p=ci&7 holds logical l=p^(row&7).
    int goff[4];
    #pragma unroll
    for (int s = 0; s < 4; ++s) {
        const int ci  = s * 256 + t;
        const int row = ci >> 3;                    // 0..127
        const int l   = (ci & 7) ^ (row & 7);
        goff[s] = row * D_DIM + l * 16;
    }

    // fragment read: lane wants logical chunks {quad, quad+4} of its row.
    // phys0 = quad ^ (row&7) (row&7 == c&7); second half at addr ^ 64.
    int slotA[4], slotB[4];   // [frag]
    #pragma unroll
    for (int f = 0; f < 4; ++f) {
        const int rA = wr * 64 + f * 16 + c;
        const int rB = wc * 64 + f * 16 + c;
        slotA[f] = rA * 128 + ((quad ^ (c & 7)) * 16);
        slotB[f] = rB * 128 + ((quad ^ (c & 7)) * 16);
    }

    floatx4 acc[4][4] = {};

    // prologue: stage K-tiles 0 and 1 (8 + 8 loads per thread in flight)
    #pragma unroll
    for (int s = 0; s < 4; ++s) {
        load16_to_lds(Ag + goff[s],       &As[0][(s * 256 + t) * 16]);
        load16_to_lds(Bg + goff[s],       &Bs[0][(s * 256 + t) * 16]);
    }
    #pragma unroll
    for (int s = 0; s < 4; ++s) {
        load16_to_lds(Ag + goff[s] + 128, &As[1][(s * 256 + t) * 16]);
        load16_to_lds(Bg + goff[s] + 128, &Bs[1][(s * 256 + t) * 16]);
    }
    __builtin_amdgcn_sched_barrier(0);

    #pragma unroll
    for (int kt = 0; kt < 6; ++kt) {
        const int cur = kt & 1;

        // tile kt's 8 loads are the oldest; tile kt+1's stay in flight
        if (kt <= 4) __builtin_amdgcn_s_waitcnt(WAIT_VM8);
        else         __builtin_amdgcn_s_waitcnt(WAIT_VM0);
        __builtin_amdgcn_sched_barrier(0);
        __builtin_amdgcn_s_barrier();        // all threads: tile kt in LDS
        __builtin_amdgcn_sched_barrier(0);

        intx8 av[4], bv[4];
        #pragma unroll
        for (int f = 0; f < 4; ++f) {
            const intx4 lo = *(const intx4*)(&As[cur][slotA[f]]);
            const intx4 hi = *(const intx4*)(&As[cur][slotA[f] ^ 64]);
            av[f] = __builtin_shufflevector(lo, hi, 0, 1, 2, 3, 4, 5, 6, 7);
        }
        #pragma unroll
        for (int f = 0; f < 4; ++f) {
            const intx4 lo = *(const intx4*)(&Bs[cur][slotB[f]]);
            const intx4 hi = *(const intx4*)(&Bs[cur][slotB[f] ^ 64]);
            bv[f] = __builtin_shufflevector(lo, hi, 0, 1, 2, 3, 4, 5, 6, 7);
        }

        __builtin_amdgcn_s_setprio(1);
        #pragma unroll
        for (int it = 0; it < 4; ++it)
            #pragma unroll
            for (int jt = 0; jt < 4; ++jt)
                acc[it][jt] = __builtin_amdgcn_mfma_scale_f32_16x16x128_f8f6f4(
                    av[it], bv[jt], acc[it][jt],
                    0, 0,                      // cbsz=fp8(e4m3), blgp=fp8(e4m3)
                    0, 0x7F7F7F7F,             // A scales: e8m0 1.0
                    0, 0x7F7F7F7F);            // B scales: e8m0 1.0
        __builtin_amdgcn_s_setprio(0);

        if (kt < 4) {
            // WAR: all waves' ds_reads of buf[cur] must retire before the
            // tile-(kt+2) loads are ISSUED (lands strictly later).
            __builtin_amdgcn_s_waitcnt(WAIT_LGKM0);
            __builtin_amdgcn_sched_barrier(0);
            __builtin_amdgcn_s_barrier();
            __builtin_amdgcn_sched_barrier(0);
            const int k0 = (kt + 2) * 128;
            #pragma unroll
            for (int s = 0; s < 4; ++s) {
                load16_to_lds(Ag + goff[s] + k0, &As[cur][(s * 256 + t) * 16]);
                load16_to_lds(Bg + goff[s] + k0, &Bs[cur][(s * 256 + t) * 16]);
            }
            __builtin_amdgcn_sched_barrier(0);
        }
    }

    const float w = wp[0];
    const int rb320 = bu * 2 + wr;      // 64-row block index, 0..319

    // per-column fixed-offset partial: sum exp(w*(cos-1)) over quadrant's 64 rows
    #pragma unroll
    for (int jt = 0; jt < 4; ++jt) {
        float sm = 0.f;
        #pragma unroll
        for (int it = 0; it < 4; ++it)
            #pragma unroll
            for (int r = 0; r < 4; ++r)
                sm += __expf(w * (acc[it][jt][r] - 1.0f));
        sm += __shfl_xor(sm, 16);
        sm += __shfl_xor(sm, 32);
        if (quad == 0)
            Psum[(size_t)rb320 * N_SPK + j0 + wc * 64 + jt * 16 + c] = sm;
    }

    // target sims: local row within m-slab == (m*1024+col)/20 (unique owner)
    #pragma unroll
    for (int it = 0; it < 4; ++it) {
        #pragma unroll
        for (int jt = 0; jt < 4; ++jt) {
            const int col = j0 + wc * 64 + jt * 16 + c;
            const int g = m * N_SPK + col;
            const int istar = g / M_UTT;
            const int rloc = rb8 * 128 + wr * 64 + it * 16 + quad * 4;
            #pragma unroll
            for (int r = 0; r < 4; ++r) {
                if (rloc + r == istar) T[g] = acc[it][jt][r];
            }
        }
    }
}

// ---------------------------------------------------------------------------
// Kernel 3: combine 16 row-block partials per (m,j) -> loss term; block sum;
// last-block writes output (ctr/accum zeroed by prep).
// term = (w*T+b) - ((w+b) + log S) = w*(T-1) - log S.
// ---------------------------------------------------------------------------
__global__ void combine_kernel(const float* __restrict__ Psum,
                               const float* __restrict__ T,
                               const float* __restrict__ wp,
                               int* __restrict__ ctr,
                               float* __restrict__ accum,
                               float* __restrict__ out) {
    const int p = blockIdx.x * 256 + threadIdx.x;
    const int m = p >> 10;
    const int j = p & 1023;
    const float w = wp[0];

    float S = 0.f;
    #pragma unroll
    for (int rb = 0; rb < 16; ++rb)
        S += Psum[(size_t)(m * 16 + rb) * N_SPK + j];
    const float term = w * (T[p] - 1.0f) - __logf(S);

    __shared__ float red[256];
    red[threadIdx.x] = term;
    __syncthreads();
    for (int o = 128; o > 0; o >>= 1) {
        if (threadIdx.x < o) red[threadIdx.x] += red[threadIdx.x + o];
        __syncthreads();
    }
    if (threadIdx.x == 0) {
        atomicAdd(accum, red[0]);
        __threadfence();
        const int old = atomicAdd(ctr, 1);
        if (old == 79) {
            const float a = atomicAdd(accum, 0.0f);   // coherent read
            out[0] = -a / (float)NM_ROWS;
        }
    }
}

// ---------------------------------------------------------------------------
extern "C" void kernel_launch(void* const* d_in, const int* in_sizes, int n_in,
                              void* d_out, int out_size, void* d_ws, size_t ws_size,
                              hipStream_t stream) {
    const float* emb = (const float*)d_in[0];
    const float* wp  = (const float*)d_in[1];
    float* out = (float*)d_out;

    char* ws = (char*)d_ws;
    //   Ehat fp8 [M][N][D] : 15,728,640  @ 0
    //   Chat fp8 [N][D]    :    786,432  @ 15,728,640
    //   Psum f32 [320][N]  :  1,310,720  @ 16,515,072
    //   T    f32 [M][N]    :     81,920  @ 17,825,792
    //   ctr i32 + accum f32:          8  @ 17,907,712
    unsigned char* ehat = (unsigned char*)(ws);
    unsigned char* chat = (unsigned char*)(ws + 15728640);
    float* Psum  = (float*)(ws + 16515072);
    float* T     = (float*)(ws + 17825792);
    int*   ctr   = (int*)  (ws + 17907712);
    float* accum = (float*)(ws + 17907716);

    prep_kernel<<<dim3(N_SPK), dim3(384), 0, stream>>>(emb, ehat, chat, ctr, accum);
    gemm_fused_kernel<<<dim3(1280), dim3(256), 0, stream>>>(ehat, chat, wp, Psum, T);
    combine_kernel<<<dim3(80), dim3(256), 0, stream>>>(Psum, T, wp, ctr, accum, out);
}